// Round 3
// baseline (191.736 us; speedup 1.0000x reference)
//
#include <hip/hip_runtime.h>

#define NVAL 15
#define VPT 4   // float4 loads per thread (16 elements), issued back-to-back for MLP

typedef float fvec4 __attribute__((ext_vector_type(4)));  // native vector: OK for nontemporal builtins

// LTQ forward: out = scale2 * (2/15) * #{i : tf[i] < x*scale1}
// tf reproduces the reference's float32 association exactly:
//   cums = sequential cumsum(a_pos);  tb[i] = s + cums[i-1];  tf[i] = tb[i] + 0.5f*a_pos[i]
__global__ __launch_bounds__(256) void ltq_fwd_kernel(
    const float* __restrict__ x,
    const float* __restrict__ start,
    const float* __restrict__ a,
    const float* __restrict__ scale1,
    const float* __restrict__ scale2,
    float* __restrict__ out,
    int n, int n4, int T /* = stride between a thread's 4 loads, in float4s */)
{
    const float s   = start[0];
    const float sc1 = scale1[0];
    const float k   = (float)(2.0 / 15.0) * scale2[0];

    float tf[NVAL];
    float cum = 0.0f;
#pragma unroll
    for (int i = 0; i < NVAL; ++i) {
        float ai = a[i];
        float ap = (ai > 1e-3f) ? ai : 1e-3f;   // jnp.where(a > EPS, a, EPS)
        float tb = s + cum;                     // s + cums[i-1]  (cums[-1] == 0)
        tf[i] = tb + 0.5f * ap;                 // tb + a_pos*0.5
        cum += ap;                              // sequential cumsum, matches np
    }

    const fvec4* __restrict__ x4 = (const fvec4*)x;
    fvec4* __restrict__ o4 = (fvec4*)out;

    const int tid = blockIdx.x * blockDim.x + threadIdx.x;

    // ---- 4 independent loads issued before any use: 4 KB in flight per wave ----
    fvec4 v[VPT];
    bool ok[VPT];
#pragma unroll
    for (int j = 0; j < VPT; ++j) {
        int i = tid + j * T;
        ok[j] = (i < n4);
        if (ok[j]) v[j] = x4[i];
    }

#pragma unroll
    for (int j = 0; j < VPT; ++j) {
        if (!ok[j]) continue;
        float xs0 = v[j].x * sc1;
        float xs1 = v[j].y * sc1;
        float xs2 = v[j].z * sc1;
        float xs3 = v[j].w * sc1;
        int c0 = 0, c1 = 0, c2 = 0, c3 = 0;
#pragma unroll
        for (int i = 0; i < NVAL; ++i) {
            float t = tf[i];
            c0 += (xs0 > t);   // strict: searchsorted side="left"
            c1 += (xs1 > t);
            c2 += (xs2 > t);
            c3 += (xs3 > t);
        }
        fvec4 r;
        r.x = k * (float)c0;
        r.y = k * (float)c1;
        r.z = k * (float)c2;
        r.w = k * (float)c3;
        __builtin_nontemporal_store(r, &o4[tid + j * T]);  // out never re-read; keep x in LLC
    }

    // scalar tail for n % 4 (not hit for this problem's N, kept for safety)
    const int tail_start = n4 << 2;
    for (int idx = tail_start + tid; idx < n; idx += T * VPT) {
        float xs = x[idx] * sc1;
        int c = 0;
#pragma unroll
        for (int i = 0; i < NVAL; ++i) c += (xs > tf[i]);
        out[idx] = k * (float)c;
    }
}

extern "C" void kernel_launch(void* const* d_in, const int* in_sizes, int n_in,
                              void* d_out, int out_size, void* d_ws, size_t ws_size,
                              hipStream_t stream) {
    const float* x      = (const float*)d_in[0];
    const float* start  = (const float*)d_in[1];
    const float* a      = (const float*)d_in[2];
    const float* scale1 = (const float*)d_in[3];
    const float* scale2 = (const float*)d_in[4];
    float* out = (float*)d_out;
    const int n = in_sizes[0];

    const int n4 = n >> 2;                       // float4 count
    const int T  = (n4 + VPT - 1) / VPT;         // per-load stride so 4 strips cover n4
    const int threads = 256;
    const int blocks  = (T + threads - 1) / threads;
    // For N = 25,690,112: T = 1,605,632 -> 6272 blocks (~24.5/CU, ~3x wave
    // oversubscription) and every thread's 4 loads are in bounds.
    ltq_fwd_kernel<<<blocks, threads, 0, stream>>>(x, start, a, scale1, scale2,
                                                   out, n, n4, T);
}

// Round 4
// 189.612 us; speedup vs baseline: 1.0112x; 1.0112x over previous
//
#include <hip/hip_runtime.h>

#define NVAL 15
#define TPB  256
#define VPT  8   // float4 loads per thread, unconditional, back-to-back (8 KB in flight/wave)

typedef float fvec4 __attribute__((ext_vector_type(4)));

__device__ __forceinline__ void make_thresholds(
    const float* __restrict__ start, const float* __restrict__ a,
    const float* __restrict__ scale1, const float* __restrict__ scale2,
    float* tf, float& sc1, float& k)
{
    const float s = start[0];
    sc1 = scale1[0];
    k   = (float)(2.0 / 15.0) * scale2[0];
    float cum = 0.0f;
#pragma unroll
    for (int i = 0; i < NVAL; ++i) {
        float ai = a[i];
        float ap = (ai > 1e-3f) ? ai : 1e-3f;   // jnp.where(a > EPS, a, EPS)
        tf[i] = (s + cum) + 0.5f * ap;          // tb[i] + a_pos[i]/2, exact fp32 association
        cum += ap;                              // sequential cumsum, matches np
    }
}

__device__ __forceinline__ fvec4 quant4(fvec4 v, const float* tf, float sc1, float k)
{
    float xs0 = v.x * sc1, xs1 = v.y * sc1, xs2 = v.z * sc1, xs3 = v.w * sc1;
    int c0 = 0, c1 = 0, c2 = 0, c3 = 0;
#pragma unroll
    for (int i = 0; i < NVAL; ++i) {
        float t = tf[i];
        c0 += (xs0 > t);   // strict > : searchsorted side="left"
        c1 += (xs1 > t);
        c2 += (xs2 > t);
        c3 += (xs3 > t);
    }
    fvec4 r;
    r.x = k * (float)c0;
    r.y = k * (float)c1;
    r.z = k * (float)c2;
    r.w = k * (float)c3;
    return r;
}

// Main kernel: exact-fit, no bounds checks, no grid-stride. Each block owns a
// contiguous TPB*VPT float4 (32 KB) span; thread loads 8 float4s 1 KB apart,
// all issued before any use.
__global__ __launch_bounds__(TPB) void ltq_main(
    const float* __restrict__ x,
    const float* __restrict__ start,
    const float* __restrict__ a,
    const float* __restrict__ scale1,
    const float* __restrict__ scale2,
    float* __restrict__ out)
{
    float tf[NVAL], sc1, k;
    make_thresholds(start, a, scale1, scale2, tf, sc1, k);

    const long long base = (long long)blockIdx.x * (TPB * VPT) + threadIdx.x;
    const fvec4* __restrict__ x4 = (const fvec4*)x + base;
    fvec4* __restrict__ o4 = (fvec4*)out + base;

    fvec4 v[VPT];
#pragma unroll
    for (int j = 0; j < VPT; ++j) v[j] = x4[j * TPB];   // 8 unconditional loads, in flight together

#pragma unroll
    for (int j = 0; j < VPT; ++j) {
        fvec4 r = quant4(v[j], tf, sc1, k);
        __builtin_nontemporal_store(r, &o4[j * TPB]);   // out never re-read
    }
}

// Generic tail: covers [f4_done, n4) float4s plus the n%4 scalar remainder.
// Not launched when the main grid tiles n exactly (true for this problem).
__global__ __launch_bounds__(TPB) void ltq_tail(
    const float* __restrict__ x,
    const float* __restrict__ start,
    const float* __restrict__ a,
    const float* __restrict__ scale1,
    const float* __restrict__ scale2,
    float* __restrict__ out,
    long long f4_done, long long n4, long long n)
{
    float tf[NVAL], sc1, k;
    make_thresholds(start, a, scale1, scale2, tf, sc1, k);

    const long long stride = (long long)gridDim.x * blockDim.x;
    const fvec4* __restrict__ x4 = (const fvec4*)x;
    fvec4* __restrict__ o4 = (fvec4*)out;
    for (long long i = f4_done + blockIdx.x * (long long)blockDim.x + threadIdx.x;
         i < n4; i += stride) {
        fvec4 r = quant4(x4[i], tf, sc1, k);
        __builtin_nontemporal_store(r, &o4[i]);
    }
    for (long long i = (n4 << 2) + blockIdx.x * (long long)blockDim.x + threadIdx.x;
         i < n; i += stride) {
        float xs = x[i] * sc1;
        int c = 0;
#pragma unroll
        for (int t = 0; t < NVAL; ++t) c += (xs > tf[t]);
        out[i] = k * (float)c;
    }
}

extern "C" void kernel_launch(void* const* d_in, const int* in_sizes, int n_in,
                              void* d_out, int out_size, void* d_ws, size_t ws_size,
                              hipStream_t stream) {
    const float* x      = (const float*)d_in[0];
    const float* start  = (const float*)d_in[1];
    const float* a      = (const float*)d_in[2];
    const float* scale1 = (const float*)d_in[3];
    const float* scale2 = (const float*)d_in[4];
    float* out = (float*)d_out;

    const long long n  = in_sizes[0];
    const long long n4 = n >> 2;
    const long long per_block = (long long)TPB * VPT;      // float4s per block
    const long long blocks = n4 / per_block;               // exact-fit main grid

    if (blocks > 0) {
        // N=25,690,112 -> n4=6,422,528 -> 3136 blocks (12.25/CU), zero remainder.
        ltq_main<<<(int)blocks, TPB, 0, stream>>>(x, start, a, scale1, scale2, out);
    }
    const long long f4_done = blocks * per_block;
    if (f4_done < n4 || (n & 3)) {
        ltq_tail<<<512, TPB, 0, stream>>>(x, start, a, scale1, scale2, out,
                                          f4_done, n4, n);
    }
}

// Round 5
// 182.243 us; speedup vs baseline: 1.0521x; 1.0404x over previous
//
#include <hip/hip_runtime.h>

#define NVAL 15
#define TPB  256
#define VPT  8   // float4 loads per thread; pinned in-flight together via sched_barrier

typedef float fvec4 __attribute__((ext_vector_type(4)));

__device__ __forceinline__ fvec4 quant4(fvec4 v, const float* tf, float sc1, float k)
{
    float xs0 = v.x * sc1, xs1 = v.y * sc1, xs2 = v.z * sc1, xs3 = v.w * sc1;
    int c0 = 0, c1 = 0, c2 = 0, c3 = 0;
#pragma unroll
    for (int i = 0; i < NVAL; ++i) {
        float t = tf[i];
        c0 += (xs0 > t);   // strict > : searchsorted side="left"
        c1 += (xs1 > t);
        c2 += (xs2 > t);
        c3 += (xs3 > t);
    }
    fvec4 r;
    r.x = k * (float)c0;
    r.y = k * (float)c1;
    r.z = k * (float)c2;
    r.w = k * (float)c3;
    return r;
}

// Exact-fit main kernel. Each block owns a contiguous 32 KB span. The 8 loads
// are issued BEFORE the scheduling barrier so the compiler cannot sink them to
// their uses (R4's VGPR=36 proved it was doing exactly that): 8 KB per wave
// genuinely outstanding. Threshold setup happens under load latency.
__global__ __launch_bounds__(TPB) void ltq_main(
    const float* __restrict__ x,
    const float* __restrict__ start,
    const float* __restrict__ a,
    const float* __restrict__ scale1,
    const float* __restrict__ scale2,
    float* __restrict__ out)
{
    const long long base = (long long)blockIdx.x * (TPB * VPT) + threadIdx.x;
    const fvec4* __restrict__ x4 = (const fvec4*)x + base;
    fvec4* __restrict__ o4 = (fvec4*)out + base;

    fvec4 v[VPT];
#pragma unroll
    for (int j = 0; j < VPT; ++j)
        v[j] = __builtin_nontemporal_load(&x4[j * TPB]);  // x never re-read: don't pollute LLC

    __builtin_amdgcn_sched_barrier(0);  // pin: all 8 loads issued before any compute

    // threshold setup overlaps the in-flight loads
    const float s   = start[0];
    const float sc1 = scale1[0];
    const float k   = (float)(2.0 / 15.0) * scale2[0];
    float tf[NVAL];
    float cum = 0.0f;
#pragma unroll
    for (int i = 0; i < NVAL; ++i) {
        float ai = a[i];
        float ap = (ai > 1e-3f) ? ai : 1e-3f;   // jnp.where(a > EPS, a, EPS)
        tf[i] = (s + cum) + 0.5f * ap;          // tb[i] + a_pos[i]/2, exact fp32 association
        cum += ap;                              // sequential cumsum, matches np
    }

#pragma unroll
    for (int j = 0; j < VPT; ++j) {
        fvec4 r = quant4(v[j], tf, sc1, k);
        o4[j * TPB] = r;                         // regular store: LLC absorbs writes
    }
}

// Generic tail (not launched when the main grid tiles n exactly — true here).
__global__ __launch_bounds__(TPB) void ltq_tail(
    const float* __restrict__ x,
    const float* __restrict__ start,
    const float* __restrict__ a,
    const float* __restrict__ scale1,
    const float* __restrict__ scale2,
    float* __restrict__ out,
    long long f4_done, long long n4, long long n)
{
    const float s   = start[0];
    const float sc1 = scale1[0];
    const float k   = (float)(2.0 / 15.0) * scale2[0];
    float tf[NVAL];
    float cum = 0.0f;
#pragma unroll
    for (int i = 0; i < NVAL; ++i) {
        float ai = a[i];
        float ap = (ai > 1e-3f) ? ai : 1e-3f;
        tf[i] = (s + cum) + 0.5f * ap;
        cum += ap;
    }

    const long long stride = (long long)gridDim.x * blockDim.x;
    const fvec4* __restrict__ x4 = (const fvec4*)x;
    fvec4* __restrict__ o4 = (fvec4*)out;
    for (long long i = f4_done + blockIdx.x * (long long)blockDim.x + threadIdx.x;
         i < n4; i += stride) {
        o4[i] = quant4(x4[i], tf, sc1, k);
    }
    for (long long i = (n4 << 2) + blockIdx.x * (long long)blockDim.x + threadIdx.x;
         i < n; i += stride) {
        float xs = x[i] * sc1;
        int c = 0;
#pragma unroll
        for (int t = 0; t < NVAL; ++t) c += (xs > tf[t]);
        out[i] = k * (float)c;
    }
}

extern "C" void kernel_launch(void* const* d_in, const int* in_sizes, int n_in,
                              void* d_out, int out_size, void* d_ws, size_t ws_size,
                              hipStream_t stream) {
    const float* x      = (const float*)d_in[0];
    const float* start  = (const float*)d_in[1];
    const float* a      = (const float*)d_in[2];
    const float* scale1 = (const float*)d_in[3];
    const float* scale2 = (const float*)d_in[4];
    float* out = (float*)d_out;

    const long long n  = in_sizes[0];
    const long long n4 = n >> 2;
    const long long per_block = (long long)TPB * VPT;      // float4s per block
    const long long blocks = n4 / per_block;               // exact-fit main grid

    if (blocks > 0) {
        // N=25,690,112 -> n4=6,422,528 -> 3136 blocks, zero remainder.
        ltq_main<<<(int)blocks, TPB, 0, stream>>>(x, start, a, scale1, scale2, out);
    }
    const long long f4_done = blocks * per_block;
    if (f4_done < n4 || (n & 3)) {
        ltq_tail<<<512, TPB, 0, stream>>>(x, start, a, scale1, scale2, out,
                                          f4_done, n4, n);
    }
}